// Round 4
// baseline (8143.864 us; speedup 1.0000x reference)
//
#include <hip/hip_runtime.h>
#include <hip/hip_bf16.h>

#define NB_OBJ   5
#define DIM_BODY 10
#define DIM_OBJ  15
#define N_PERM   20
#define HID      256
#define DMP      128
#define ACT      4
#define BATCH    32768
#define GOAL_DIM 30
#define DIN      19          // 10 body + 3 dg + 3 src + 3 tgt
#define OBS_LEN  85          // DIM_BODY + NB_OBJ*DIM_OBJ

// dtype contract (R1-R3 post-mortem): reference is fp32 end-to-end ->
// inputs are const float*, output is float*. The test's "bf16" label is
// its comparison policy, not the buffer dtype.

__global__ __launch_bounds__(256) void actor_fused_kernel(
    const float* __restrict__ obs, const float* __restrict__ ag, const float* __restrict__ g,
    const float* __restrict__ W1, const float* __restrict__ b1,
    const float* __restrict__ W2, const float* __restrict__ b2,
    const float* __restrict__ Wq, const float* __restrict__ bq,
    const float* __restrict__ Wk, const float* __restrict__ bk,
    const float* __restrict__ Wv, const float* __restrict__ bv,
    const float* __restrict__ Wr, const float* __restrict__ br,
    const float* __restrict__ Wm, const float* __restrict__ bm,
    const float* __restrict__ Ws, const float* __restrict__ bs,
    const int*  __restrict__ edges, const int* __restrict__ pred_ids,
    float* __restrict__ out)
{
    const int b   = blockIdx.x;
    const int tid = threadIdx.x;

    __shared__ float s_obs[OBS_LEN];
    __shared__ float s_dg[GOAL_DIM];
    __shared__ int   s_edges[N_PERM * 2];
    __shared__ int   s_pred[N_PERM * 3];
    __shared__ float s_inp[N_PERM][DIN];
    // s_hall dead after stage 3; s_q/s_k overlay it (20*256*4 = 2*20*128*4)
    __shared__ union {
        float hall[N_PERM][HID];
        struct { float q[N_PERM][DMP]; float k[N_PERM][DMP]; } qk;
    } u;
    __shared__ float s_x[N_PERM][DMP];
    __shared__ float s_v[N_PERM][DMP];
    __shared__ float s_sc[N_PERM][N_PERM];
    __shared__ float s_cs[N_PERM];
    __shared__ float s_pooled[DMP];
    __shared__ float s_hr[HID];

    // ---- stage 0: per-element inputs -> LDS ----
    if (tid < OBS_LEN)   s_obs[tid] = obs[b * OBS_LEN + tid];
    if (tid < GOAL_DIM)  s_dg[tid]  = g[b * GOAL_DIM + tid] - ag[b * GOAL_DIM + tid];
    if (tid < N_PERM*2)  s_edges[tid] = edges[tid];
    if (tid < N_PERM*3)  s_pred[tid]  = pred_ids[tid];
    __syncthreads();

    // ---- stage 1: build all 20 edge input vectors (19 features) ----
    for (int idx = tid; idx < N_PERM * DIN; idx += 256) {
        int p = idx / DIN, c = idx % DIN;
        float v;
        if      (c < 10) v = s_obs[c];
        else if (c < 13) v = s_dg[s_pred[p * 3 + (c - 10)]];
        else if (c < 16) v = s_obs[DIM_BODY + s_edges[p * 2 + 0] * DIM_OBJ + (c - 13)];
        else             v = s_obs[DIM_BODY + s_edges[p * 2 + 1] * DIM_OBJ + (c - 16)];
        s_inp[p][c] = v;
    }
    __syncthreads();

    // ---- stage 2: MLP1 (19 -> 256), thread t owns column t ----
    {
        float w1c[DIN];
        #pragma unroll
        for (int kk = 0; kk < DIN; ++kk) w1c[kk] = W1[kk * HID + tid];
        float bb = b1[tid];
        for (int p = 0; p < N_PERM; ++p) {
            float acc = bb;
            #pragma unroll
            for (int kk = 0; kk < DIN; ++kk) acc += s_inp[p][kk] * w1c[kk];
            u.hall[p][tid] = fmaxf(acc, 0.f);
        }
    }
    __syncthreads();

    // ---- stage 3: MLP2 (256 -> 128) ----
    for (int it = 0; it < (N_PERM * DMP) / 256; ++it) {
        int idx = tid + it * 256;
        int p = idx >> 7, j = idx & (DMP - 1);
        float acc = b2[j];
        for (int kk = 0; kk < HID; ++kk)
            acc += u.hall[p][kk] * W2[kk * DMP + j];
        s_x[p][j] = fmaxf(acc, 0.f);
    }
    __syncthreads();   // last reads of u.hall; u.qk writes begin below

    // ---- stage 4: Q,K,V (128 -> 128 each) ----
    for (int it = 0; it < (N_PERM * DMP) / 256; ++it) {
        int idx = tid + it * 256;
        int p = idx >> 7, j = idx & (DMP - 1);
        float aq = bq[j], ak = bk[j], av = bv[j];
        for (int kk = 0; kk < DMP; ++kk) {
            float xv = s_x[p][kk];
            aq += xv * Wq[kk * DMP + j];
            ak += xv * Wk[kk * DMP + j];
            av += xv * Wv[kk * DMP + j];
        }
        u.qk.q[p][j] = aq; u.qk.k[p][j] = ak; s_v[p][j] = av;
    }
    __syncthreads();

    // ---- stage 5: scores = q k^T / sqrt(128) ----
    for (int idx = tid; idx < N_PERM * N_PERM; idx += 256) {
        int p = idx / N_PERM, qq = idx % N_PERM;
        float s = 0.f;
        for (int kk = 0; kk < DMP; ++kk) s += u.qk.q[p][kk] * u.qk.k[qq][kk];
        s_sc[p][qq] = s * 0.08838834764831845f;   // 1/sqrt(128)
    }
    __syncthreads();

    // ---- stage 6: row softmax, then column sums ----
    if (tid < N_PERM) {
        float m = -1e30f;
        for (int qq = 0; qq < N_PERM; ++qq) m = fmaxf(m, s_sc[tid][qq]);
        float sum = 0.f;
        for (int qq = 0; qq < N_PERM; ++qq) { float e = __expf(s_sc[tid][qq] - m); s_sc[tid][qq] = e; sum += e; }
        float inv = 1.f / sum;
        for (int qq = 0; qq < N_PERM; ++qq) s_sc[tid][qq] *= inv;
    }
    __syncthreads();
    if (tid < N_PERM) {
        float cs = 0.f;
        for (int p = 0; p < N_PERM; ++p) cs += s_sc[p][tid];
        s_cs[tid] = cs;
    }
    __syncthreads();

    // ---- stage 7: pooled = colsum(attn) @ v ----
    if (tid < DMP) {
        float acc = 0.f;
        for (int qq = 0; qq < N_PERM; ++qq) acc += s_cs[qq] * s_v[qq][tid];
        s_pooled[tid] = acc;
    }
    __syncthreads();

    // ---- stage 8: hr = relu(pooled @ Wr + br), 128 -> 256 ----
    {
        float acc = br[tid];
        for (int kk = 0; kk < DMP; ++kk)
            acc += s_pooled[kk] * Wr[kk * HID + tid];
        s_hr[tid] = fmaxf(acc, 0.f);
    }
    __syncthreads();

    // ---- stage 9: heads (256 -> 4 mean, 256 -> 4 log_std), fp32 stores ----
    if (tid < 2 * ACT) {
        int a = tid & (ACT - 1);
        bool is_mean = tid < ACT;
        const float* W = is_mean ? Wm : Ws;
        float acc = is_mean ? bm[a] : bs[a];
        for (int kk = 0; kk < HID; ++kk) acc += s_hr[kk] * W[kk * ACT + a];
        if (!is_mean) acc = fminf(fmaxf(acc, -20.f), 2.f);
        out[(is_mean ? 0 : BATCH * ACT) + b * ACT + a] = acc;
    }
}

extern "C" void kernel_launch(void* const* d_in, const int* in_sizes, int n_in,
                              void* d_out, int out_size, void* d_ws, size_t ws_size,
                              hipStream_t stream) {
    (void)in_sizes; (void)n_in; (void)d_ws; (void)ws_size; (void)out_size;
    const float* obs = (const float*)d_in[0];
    const float* ag  = (const float*)d_in[1];
    const float* g   = (const float*)d_in[2];
    const float* W1  = (const float*)d_in[3];
    const float* b1  = (const float*)d_in[4];
    const float* W2  = (const float*)d_in[5];
    const float* b2  = (const float*)d_in[6];
    const float* Wq  = (const float*)d_in[7];
    const float* bq  = (const float*)d_in[8];
    const float* Wk  = (const float*)d_in[9];
    const float* bk  = (const float*)d_in[10];
    const float* Wv  = (const float*)d_in[11];
    const float* bv  = (const float*)d_in[12];
    const float* Wr  = (const float*)d_in[13];
    const float* br  = (const float*)d_in[14];
    const float* Wm  = (const float*)d_in[15];
    const float* bm  = (const float*)d_in[16];
    const float* Ws  = (const float*)d_in[17];
    const float* bs  = (const float*)d_in[18];
    const int*  edges    = (const int*)d_in[19];
    const int*  pred_ids = (const int*)d_in[20];
    float* out = (float*)d_out;

    actor_fused_kernel<<<BATCH, 256, 0, stream>>>(
        obs, ag, g, W1, b1, W2, b2, Wq, bq, Wk, bk, Wv, bv,
        Wr, br, Wm, bm, Ws, bs, edges, pred_ids, out);
}

// Round 5
// 1983.276 us; speedup vs baseline: 4.1063x; 4.1063x over previous
//
#include <hip/hip_runtime.h>
#include <hip/hip_bf16.h>

#define NB_OBJ   5
#define DIM_BODY 10
#define DIM_OBJ  15
#define N_PERM   20
#define HID      256
#define DMP      128
#define ACT      4
#define BATCH    32768
#define GOAL_DIM 30
#define DIN      19
#define OBS_LEN  85
#define TB       2                 // batch elements per block
#define MROWS    (TB * N_PERM)     // 40 edge rows per block

typedef __hip_bfloat16 bf16;

__device__ __forceinline__ float b2f(bf16 x) { return __bfloat162float(x); }
__device__ __forceinline__ bf16  f2b(float x) { return __float2bfloat16(x); }

// dtype contract (R1-R4): fp32 in, fp32 out; test compares at bf16 tolerance.
// R4 counters: VALUBusy 20%, latency-bound 1-load:1-FMA inner loops.
// This version: register blocking (4 cols x 5 rows per thread, float4 weight
// loads, 5x weight reuse), TB=2 to halve per-block weight re-reads.
// LDS ~72KB -> 2 blocks/CU.
__global__ __launch_bounds__(256, 2) void actor_fused_kernel(
    const float* __restrict__ obs, const float* __restrict__ ag, const float* __restrict__ g,
    const float* __restrict__ W1, const float* __restrict__ b1,
    const float* __restrict__ W2, const float* __restrict__ b2,
    const float* __restrict__ Wq, const float* __restrict__ bq,
    const float* __restrict__ Wk, const float* __restrict__ bk,
    const float* __restrict__ Wv, const float* __restrict__ bv,
    const float* __restrict__ Wr, const float* __restrict__ br,
    const float* __restrict__ Wm, const float* __restrict__ bm,
    const float* __restrict__ Ws, const float* __restrict__ bs,
    const int*  __restrict__ edges, const int* __restrict__ pred_ids,
    float* __restrict__ out)
{
    const int b0  = blockIdx.x * TB;
    const int tid = threadIdx.x;

    __shared__ float s_obs[TB][OBS_LEN];
    __shared__ float s_dg[TB][GOAL_DIM];
    __shared__ int   s_edges[N_PERM * 2];
    __shared__ int   s_pred[N_PERM * 3];
    __shared__ float s_inp[MROWS][20];            // 19 padded to 20 (pad = 0)
    // hall (40x256 fp32, 40960B) dead after MLP2; q/k (rows padded to 132
    // floats to break bank alignment in the scores stage) overlay it.
    __shared__ union {
        float hall[MROWS][HID];                   // 40960 B
        struct { float q[MROWS][132]; float k[MROWS][132]; } qk;  // 42240 B
    } u;
    __shared__ bf16  s_x[MROWS][DMP];             // 10240 B (storage-only bf16)
    __shared__ bf16  s_v[MROWS][DMP];             // 10240 B
    __shared__ float s_sc[TB][N_PERM][N_PERM];
    __shared__ float s_cs[TB][N_PERM];
    __shared__ float s_pooled[TB][DMP];
    __shared__ float s_hr[TB][HID];

    // ---- stage 0: inputs -> LDS ----
    if (tid < TB * OBS_LEN) {
        int bi = tid / OBS_LEN, c = tid % OBS_LEN;
        s_obs[bi][c] = obs[(b0 + bi) * OBS_LEN + c];
    }
    if (tid < TB * GOAL_DIM) {
        int bi = tid / GOAL_DIM, c = tid % GOAL_DIM;
        s_dg[bi][c] = g[(b0 + bi) * GOAL_DIM + c] - ag[(b0 + bi) * GOAL_DIM + c];
    }
    if (tid < N_PERM * 2) s_edges[tid] = edges[tid];
    if (tid < N_PERM * 3) s_pred[tid]  = pred_ids[tid];
    __syncthreads();

    // ---- stage 1: build 40 x 19(+pad) edge inputs ----
    for (int idx = tid; idx < MROWS * 20; idx += 256) {
        int m = idx / 20, c = idx % 20;
        int bi = m / N_PERM, p = m % N_PERM;
        float v = 0.f;
        if      (c < 10) v = s_obs[bi][c];
        else if (c < 13) v = s_dg[bi][s_pred[p * 3 + (c - 10)]];
        else if (c < 16) v = s_obs[bi][DIM_BODY + s_edges[p * 2 + 0] * DIM_OBJ + (c - 13)];
        else if (c < 19) v = s_obs[bi][DIM_BODY + s_edges[p * 2 + 1] * DIM_OBJ + (c - 16)];
        s_inp[m][c] = v;  // c==19 -> 0
    }
    __syncthreads();

    // ---- stage 2: MLP1 (19 -> 256); thread t owns W1 column t ----
    {
        float w1c[20];
        #pragma unroll
        for (int kk = 0; kk < DIN; ++kk) w1c[kk] = W1[kk * HID + tid];
        w1c[19] = 0.f;
        const float bb = b1[tid];
        for (int m = 0; m < MROWS; ++m) {
            const float4* ip4 = (const float4*)s_inp[m];
            float acc = bb;
            #pragma unroll
            for (int k4 = 0; k4 < 5; ++k4) {
                float4 iv = ip4[k4];
                acc += iv.x * w1c[4*k4+0] + iv.y * w1c[4*k4+1]
                     + iv.z * w1c[4*k4+2] + iv.w * w1c[4*k4+3];
            }
            u.hall[m][tid] = fmaxf(acc, 0.f);
        }
    }
    __syncthreads();

    // ---- stage 3: MLP2 (256 -> 128); thread = 4 cols x 5 rows ----
    const int jgrp = tid & 31;          // j0 = jgrp*4
    const int p0   = (tid >> 5) * 5;    // 8 groups of 5 rows
    {
        const float4* W2v = (const float4*)W2;          // [256][32]
        const float4  bb  = ((const float4*)b2)[jgrp];
        float acc[5][4];
        #pragma unroll
        for (int pp = 0; pp < 5; ++pp) {
            acc[pp][0] = bb.x; acc[pp][1] = bb.y; acc[pp][2] = bb.z; acc[pp][3] = bb.w;
        }
        #pragma unroll 4
        for (int kk = 0; kk < HID; ++kk) {
            float4 w = W2v[kk * 32 + jgrp];
            #pragma unroll
            for (int pp = 0; pp < 5; ++pp) {
                float h = u.hall[p0 + pp][kk];
                acc[pp][0] += h * w.x; acc[pp][1] += h * w.y;
                acc[pp][2] += h * w.z; acc[pp][3] += h * w.w;
            }
        }
        __syncthreads();   // all hall reads done (q/k will overwrite it)
        #pragma unroll
        for (int pp = 0; pp < 5; ++pp)
            #pragma unroll
            for (int jj = 0; jj < 4; ++jj)
                s_x[p0 + pp][jgrp * 4 + jj] = f2b(fmaxf(acc[pp][jj], 0.f));
    }
    __syncthreads();

    // ---- stage 4: Q,K,V (128 -> 3x128); same mapping, 60 accumulators ----
    {
        const float4* Wqv = (const float4*)Wq;
        const float4* Wkv = (const float4*)Wk;
        const float4* Wvv = (const float4*)Wv;
        const float4 bq4 = ((const float4*)bq)[jgrp];
        const float4 bk4 = ((const float4*)bk)[jgrp];
        const float4 bv4 = ((const float4*)bv)[jgrp];
        float aq[5][4], ak[5][4], av[5][4];
        #pragma unroll
        for (int pp = 0; pp < 5; ++pp) {
            aq[pp][0]=bq4.x; aq[pp][1]=bq4.y; aq[pp][2]=bq4.z; aq[pp][3]=bq4.w;
            ak[pp][0]=bk4.x; ak[pp][1]=bk4.y; ak[pp][2]=bk4.z; ak[pp][3]=bk4.w;
            av[pp][0]=bv4.x; av[pp][1]=bv4.y; av[pp][2]=bv4.z; av[pp][3]=bv4.w;
        }
        #pragma unroll 2
        for (int kk = 0; kk < DMP; ++kk) {
            float4 wq = Wqv[kk * 32 + jgrp];
            float4 wk = Wkv[kk * 32 + jgrp];
            float4 wv = Wvv[kk * 32 + jgrp];
            #pragma unroll
            for (int pp = 0; pp < 5; ++pp) {
                float xv = b2f(s_x[p0 + pp][kk]);
                aq[pp][0] += xv * wq.x; aq[pp][1] += xv * wq.y; aq[pp][2] += xv * wq.z; aq[pp][3] += xv * wq.w;
                ak[pp][0] += xv * wk.x; ak[pp][1] += xv * wk.y; ak[pp][2] += xv * wk.z; ak[pp][3] += xv * wk.w;
                av[pp][0] += xv * wv.x; av[pp][1] += xv * wv.y; av[pp][2] += xv * wv.z; av[pp][3] += xv * wv.w;
            }
        }
        #pragma unroll
        for (int pp = 0; pp < 5; ++pp)
            #pragma unroll
            for (int jj = 0; jj < 4; ++jj) {
                u.qk.q[p0 + pp][jgrp * 4 + jj] = aq[pp][jj];
                u.qk.k[p0 + pp][jgrp * 4 + jj] = ak[pp][jj];
                s_v[p0 + pp][jgrp * 4 + jj]    = f2b(av[pp][jj]);
            }
    }
    __syncthreads();

    // ---- stage 5: scores = q k^T / sqrt(128) ----
    for (int idx = tid; idx < TB * N_PERM * N_PERM; idx += 256) {
        int bi = idx / (N_PERM * N_PERM), r = idx % (N_PERM * N_PERM);
        int p = r / N_PERM, qq = r % N_PERM;
        const float4* qrow = (const float4*)u.qk.q[bi * N_PERM + p];
        const float4* krow = (const float4*)u.qk.k[bi * N_PERM + qq];
        float s = 0.f;
        #pragma unroll 8
        for (int t = 0; t < 32; ++t) {
            float4 a = qrow[t], c = krow[t];
            s += a.x * c.x + a.y * c.y + a.z * c.z + a.w * c.w;
        }
        s_sc[bi][p][qq] = s * 0.08838834764831845f;
    }
    __syncthreads();

    // ---- stage 6: row softmax + column sums ----
    if (tid < TB * N_PERM) {
        int bi = tid / N_PERM, row = tid % N_PERM;
        float m = -1e30f;
        for (int qq = 0; qq < N_PERM; ++qq) m = fmaxf(m, s_sc[bi][row][qq]);
        float sum = 0.f;
        for (int qq = 0; qq < N_PERM; ++qq) {
            float e = __expf(s_sc[bi][row][qq] - m);
            s_sc[bi][row][qq] = e; sum += e;
        }
        float inv = 1.f / sum;
        for (int qq = 0; qq < N_PERM; ++qq) s_sc[bi][row][qq] *= inv;
    }
    __syncthreads();
    if (tid < TB * N_PERM) {
        int bi = tid / N_PERM, col = tid % N_PERM;
        float cs = 0.f;
        for (int p = 0; p < N_PERM; ++p) cs += s_sc[bi][p][col];
        s_cs[bi][col] = cs;
    }
    __syncthreads();

    // ---- stage 7: pooled = colsum(attn) @ v ----
    {
        int bi = tid >> 7, j = tid & (DMP - 1);
        float acc = 0.f;
        #pragma unroll
        for (int qq = 0; qq < N_PERM; ++qq)
            acc += s_cs[bi][qq] * b2f(s_v[bi * N_PERM + qq][j]);
        s_pooled[bi][j] = acc;
    }
    __syncthreads();

    // ---- stage 8: hr = relu(pooled @ Wr + br); Wr load shared across bi ----
    {
        float a0 = br[tid], a1 = a0;
        #pragma unroll 4
        for (int kk = 0; kk < DMP; ++kk) {
            float wr = Wr[kk * HID + tid];
            a0 += s_pooled[0][kk] * wr;
            a1 += s_pooled[1][kk] * wr;
        }
        s_hr[0][tid] = fmaxf(a0, 0.f);
        s_hr[1][tid] = fmaxf(a1, 0.f);
    }
    __syncthreads();

    // ---- stage 9: heads ----
    if (tid < TB * 2 * ACT) {
        int bi = tid / (2 * ACT), r = tid % (2 * ACT);
        bool is_mean = r < ACT;
        int a = r & (ACT - 1);
        const float* W = is_mean ? Wm : Ws;
        float acc = is_mean ? bm[a] : bs[a];
        for (int kk = 0; kk < HID; ++kk) acc += s_hr[bi][kk] * W[kk * ACT + a];
        if (!is_mean) acc = fminf(fmaxf(acc, -20.f), 2.f);
        out[(is_mean ? 0 : BATCH * ACT) + (b0 + bi) * ACT + a] = acc;
    }
}

extern "C" void kernel_launch(void* const* d_in, const int* in_sizes, int n_in,
                              void* d_out, int out_size, void* d_ws, size_t ws_size,
                              hipStream_t stream) {
    (void)in_sizes; (void)n_in; (void)d_ws; (void)ws_size; (void)out_size;
    const float* obs = (const float*)d_in[0];
    const float* ag  = (const float*)d_in[1];
    const float* g   = (const float*)d_in[2];
    const float* W1  = (const float*)d_in[3];
    const float* b1  = (const float*)d_in[4];
    const float* W2  = (const float*)d_in[5];
    const float* b2  = (const float*)d_in[6];
    const float* Wq  = (const float*)d_in[7];
    const float* bq  = (const float*)d_in[8];
    const float* Wk  = (const float*)d_in[9];
    const float* bk  = (const float*)d_in[10];
    const float* Wv  = (const float*)d_in[11];
    const float* bv  = (const float*)d_in[12];
    const float* Wr  = (const float*)d_in[13];
    const float* br  = (const float*)d_in[14];
    const float* Wm  = (const float*)d_in[15];
    const float* bm  = (const float*)d_in[16];
    const float* Ws  = (const float*)d_in[17];
    const float* bs  = (const float*)d_in[18];
    const int*  edges    = (const int*)d_in[19];
    const int*  pred_ids = (const int*)d_in[20];
    float* out = (float*)d_out;

    actor_fused_kernel<<<BATCH / TB, 256, 0, stream>>>(
        obs, ag, g, W1, b1, W2, b2, Wq, bq, Wk, bk, Wv, bv,
        Wr, br, Wm, bm, Ws, bs, edges, pred_ids, out);
}

// Round 6
// 424.978 us; speedup vs baseline: 19.1630x; 4.6668x over previous
//
#include <hip/hip_runtime.h>
#include <hip/hip_bf16.h>
#include <string.h>

#define NB_OBJ   5
#define DIM_BODY 10
#define DIM_OBJ  15
#define N_PERM   20
#define HID      256
#define DMP      128
#define ACT      4
#define BATCH    32768
#define GOAL_DIM 30
#define DIN      19
#define OBS_LEN  85
#define TB       4                 // batch elements per block
#define MROWS    80                // TB * N_PERM

typedef __hip_bfloat16 bf16;
typedef __attribute__((ext_vector_type(8))) short s16x8;   // 8 bf16 = 4 VGPRs
typedef __attribute__((ext_vector_type(4))) float f32x4;

#define MFMA16(a, b, c) __builtin_amdgcn_mfma_f32_16x16x32_bf16((a), (b), (c), 0, 0, 0)

// ---- packed-weight offsets in d_ws (bf16 elements) ----
// tiled layout: [nt][kt][c(4)][n16(16)][j(8)], value = W[kt*32+c*8+j][nt*16+n16]
#define OFF_W1   0        // NT=16, KT=1  -> 8192
#define OFF_W2   8192     // NT=8,  KT=8  -> 32768
#define OFF_WQ   40960    // NT=8,  KT=4  -> 16384
#define OFF_WK   57344
#define OFF_WV   73728
#define OFF_WR   90112    // plain [128][256] -> 32768
#define PACK_TOTAL 122880

__device__ __forceinline__ float b2f(bf16 x) { return __bfloat162float(x); }
__device__ __forceinline__ bf16  f2b(float x) { return __float2bfloat16(x); }

// XOR block swizzle: element [m][k] lives at column ((k>>3) ^ (m&bprm))*8 + (k&7)
__device__ __forceinline__ int swz(int m, int k, int bprm) {
    return ((((k >> 3) ^ (m & bprm)) << 3) | (k & 7));
}
__device__ __forceinline__ s16x8 frag_lds(const bf16* base, int m, int stride, int kof, int bprm) {
    int phys = (((kof >> 3) ^ (m & bprm)) << 3);
    return *(const s16x8*)(base + m * stride + phys);
}

// ================= prepack: fp32 weights -> bf16 B-fragment layout =================
__device__ __forceinline__ void pack_tiled(const float* __restrict__ W, int Kact, int N,
                                           int KT, bf16* __restrict__ dst, int idx) {
    int tile = idx >> 9;            // nt*KT + kt
    int r    = idx & 511;
    int kt   = tile % KT, nt = tile / KT;
    int c    = r >> 7;
    int rem  = r & 127;
    int n16  = rem >> 3, j = rem & 7;
    int k    = kt * 32 + c * 8 + j;
    float v  = (k < Kact) ? W[k * N + nt * 16 + n16] : 0.f;
    dst[idx] = __float2bfloat16(v);
}

__global__ __launch_bounds__(256) void prepack_kernel(
    const float* __restrict__ W1, const float* __restrict__ W2,
    const float* __restrict__ Wq, const float* __restrict__ Wk,
    const float* __restrict__ Wv, const float* __restrict__ Wr,
    bf16* __restrict__ ws) {
    int idx = blockIdx.x * 256 + threadIdx.x;
    if      (idx < 8192)   pack_tiled(W1,  19, 256, 1, ws + OFF_W1, idx);
    else if (idx < 40960)  pack_tiled(W2, 256, 128, 8, ws + OFF_W2, idx - 8192);
    else if (idx < 57344)  pack_tiled(Wq, 128, 128, 4, ws + OFF_WQ, idx - 40960);
    else if (idx < 73728)  pack_tiled(Wk, 128, 128, 4, ws + OFF_WK, idx - 57344);
    else if (idx < 90112)  pack_tiled(Wv, 128, 128, 4, ws + OFF_WV, idx - 73728);
    else if (idx < PACK_TOTAL) { int i = idx - 90112; ws[OFF_WR + i] = __float2bfloat16(Wr[i]); }
}

// ================= main fused kernel =================
__global__ __launch_bounds__(256, 2) void actor_main(
    const float* __restrict__ obs, const float* __restrict__ ag, const float* __restrict__ g,
    const float* __restrict__ b1, const float* __restrict__ b2v,
    const float* __restrict__ bqv, const float* __restrict__ bkv, const float* __restrict__ bvv,
    const float* __restrict__ brv,
    const float* __restrict__ Wm, const float* __restrict__ bm,
    const float* __restrict__ Wsc, const float* __restrict__ bsv,
    const int* __restrict__ edges, const int* __restrict__ pred_ids,
    const bf16* __restrict__ wp, float* __restrict__ out)
{
    const int b0   = blockIdx.x * TB;
    const int tid  = threadIdx.x;
    const int lane = tid & 63;
    const int wav  = tid >> 6;
    const int l15  = lane & 15;
    const int lq   = lane >> 4;

    // ---- LDS: three union regions, total exactly 81,920 B (2 blocks/CU) ----
    __shared__ __align__(16) union {
        struct {
            float obs_[TB][OBS_LEN];
            float dg[TB][GOAL_DIM];
            int   edg[N_PERM * 2];
            int   prd[N_PERM * 3];
            bf16  inp[MROWS][40];       // K padded 19->32, row stride 40 (bank spread)
        } a;                            // 8,640 B (dead after MLP1)
        bf16 v[MROWS][DMP];             // 20,480 B (written at QKV)
    } rA;
    __shared__ __align__(16) union {
        bf16 hall[MROWS][HID];          // 40,960 B (dead after MLP2)
        struct { bf16 q[MROWS][DMP]; bf16 k[MROWS][DMP]; } qk;
    } rB;
    __shared__ __align__(16) union {
        bf16 x[MROWS][DMP];             // 20,480 B (dead after QKV)
        struct {
            union { float sc[TB][N_PERM][N_PERM]; float red[32][8]; } s;
            float cs[TB][N_PERM];
            float pooled[TB][DMP];
            float hr[TB][HID];
        } p;                            // 12,864 B
    } rC;

    const f32x4 zf = {0.f, 0.f, 0.f, 0.f};

    // ---- stage 0: inputs -> LDS (flat copies) ----
    for (int i = tid; i < TB * OBS_LEN; i += 256)
        ((float*)rA.a.obs_)[i] = obs[b0 * OBS_LEN + i];
    for (int i = tid; i < TB * GOAL_DIM; i += 256)
        ((float*)rA.a.dg)[i] = g[b0 * GOAL_DIM + i] - ag[b0 * GOAL_DIM + i];
    if (tid < N_PERM * 2) rA.a.edg[tid] = edges[tid];
    if (tid < N_PERM * 3) rA.a.prd[tid] = pred_ids[tid];
    __syncthreads();

    // ---- stage 1: build 80 x 32 (19 + zero pad) edge inputs, bf16 ----
    for (int idx = tid; idx < MROWS * 32; idx += 256) {
        int m = idx >> 5, c = idx & 31;
        int bi = m / N_PERM, p = m - bi * N_PERM;
        float v = 0.f;
        if      (c < 10) v = rA.a.obs_[bi][c];
        else if (c < 13) v = rA.a.dg[bi][rA.a.prd[p * 3 + (c - 10)]];
        else if (c < 16) v = rA.a.obs_[bi][DIM_BODY + rA.a.edg[p * 2 + 0] * DIM_OBJ + (c - 13)];
        else if (c < 19) v = rA.a.obs_[bi][DIM_BODY + rA.a.edg[p * 2 + 1] * DIM_OBJ + (c - 16)];
        rA.a.inp[m][c] = f2b(v);
    }
    __syncthreads();

    // ---- stage 2: MLP1 (19->256) MFMA. wave w: nt in [4w, 4w+4), mt 0..4, KT=1 ----
    {
        s16x8 afr[5];
        #pragma unroll
        for (int mt = 0; mt < 5; ++mt)
            afr[mt] = *(const s16x8*)(&rA.a.inp[mt * 16 + l15][lq * 8]);
        #pragma unroll
        for (int ntl = 0; ntl < 4; ++ntl) {
            int nt = wav * 4 + ntl;
            s16x8 bfr = *(const s16x8*)(wp + OFF_W1 + nt * 512 + (lq * 16 + l15) * 8);
            float bias = b1[nt * 16 + l15];
            #pragma unroll
            for (int mt = 0; mt < 5; ++mt) {
                f32x4 acc = MFMA16(afr[mt], bfr, zf);
                #pragma unroll
                for (int r = 0; r < 4; ++r) {
                    int row = mt * 16 + lq * 4 + r;
                    rB.hall[row][swz(row, nt * 16 + l15, 31)] =
                        f2b(fmaxf(acc[r] + bias, 0.f));
                }
            }
        }
    }
    __syncthreads();

    // ---- stage 3: MLP2 (256->128) MFMA. wave w: nt {2w,2w+1}, KT=8 ----
    {
        int nt0 = wav * 2, nt1 = nt0 + 1;
        f32x4 acc0[5], acc1[5];
        #pragma unroll
        for (int mt = 0; mt < 5; ++mt) { acc0[mt] = zf; acc1[mt] = zf; }
        #pragma unroll
        for (int kt = 0; kt < 8; ++kt) {
            s16x8 bf0 = *(const s16x8*)(wp + OFF_W2 + (nt0 * 8 + kt) * 512 + (lq * 16 + l15) * 8);
            s16x8 bf1 = *(const s16x8*)(wp + OFF_W2 + (nt1 * 8 + kt) * 512 + (lq * 16 + l15) * 8);
            #pragma unroll
            for (int mt = 0; mt < 5; ++mt) {
                s16x8 a = frag_lds(&rB.hall[0][0], mt * 16 + l15, HID, kt * 32 + lq * 8, 31);
                acc0[mt] = MFMA16(a, bf0, acc0[mt]);
                acc1[mt] = MFMA16(a, bf1, acc1[mt]);
            }
        }
        float bias0 = b2v[nt0 * 16 + l15], bias1 = b2v[nt1 * 16 + l15];
        #pragma unroll
        for (int mt = 0; mt < 5; ++mt)
            #pragma unroll
            for (int r = 0; r < 4; ++r) {
                int row = mt * 16 + lq * 4 + r;
                rC.x[row][swz(row, nt0 * 16 + l15, 15)] = f2b(fmaxf(acc0[mt][r] + bias0, 0.f));
                rC.x[row][swz(row, nt1 * 16 + l15, 15)] = f2b(fmaxf(acc1[mt][r] + bias1, 0.f));
            }
    }
    __syncthreads();   // hall reads done -> q/k may overwrite; x visible to all

    // ---- stage 4: QKV (128 -> 3x128) MFMA. per matrix: nt {2w,2w+1}, KT=4 ----
    #pragma unroll
    for (int mat = 0; mat < 3; ++mat) {
        const bf16*  wpm  = wp + (mat == 0 ? OFF_WQ : (mat == 1 ? OFF_WK : OFF_WV));
        const float* bias = (mat == 0 ? bqv : (mat == 1 ? bkv : bvv));
        int nt0 = wav * 2, nt1 = nt0 + 1;
        f32x4 acc0[5], acc1[5];
        #pragma unroll
        for (int mt = 0; mt < 5; ++mt) { acc0[mt] = zf; acc1[mt] = zf; }
        #pragma unroll
        for (int kt = 0; kt < 4; ++kt) {
            s16x8 bf0 = *(const s16x8*)(wpm + (nt0 * 4 + kt) * 512 + (lq * 16 + l15) * 8);
            s16x8 bf1 = *(const s16x8*)(wpm + (nt1 * 4 + kt) * 512 + (lq * 16 + l15) * 8);
            #pragma unroll
            for (int mt = 0; mt < 5; ++mt) {
                s16x8 a = frag_lds(&rC.x[0][0], mt * 16 + l15, DMP, kt * 32 + lq * 8, 15);
                acc0[mt] = MFMA16(a, bf0, acc0[mt]);
                acc1[mt] = MFMA16(a, bf1, acc1[mt]);
            }
        }
        float bias0 = bias[nt0 * 16 + l15], bias1 = bias[nt1 * 16 + l15];
        #pragma unroll
        for (int mt = 0; mt < 5; ++mt)
            #pragma unroll
            for (int r = 0; r < 4; ++r) {
                int row = mt * 16 + lq * 4 + r;
                int c0 = nt0 * 16 + l15, c1 = nt1 * 16 + l15;
                float v0 = acc0[mt][r] + bias0, v1 = acc1[mt][r] + bias1;  // no relu
                if (mat == 0) {
                    rB.qk.q[row][swz(row, c0, 15)] = f2b(v0);
                    rB.qk.q[row][swz(row, c1, 15)] = f2b(v1);
                } else if (mat == 1) {
                    rB.qk.k[row][swz(row, c0, 15)] = f2b(v0);
                    rB.qk.k[row][swz(row, c1, 15)] = f2b(v1);
                } else {
                    rA.v[row][c0] = f2b(v0);      // v unswizzled (scalar reads later)
                    rA.v[row][c1] = f2b(v1);
                }
            }
    }
    __syncthreads();

    // ---- stage 5: scores = q k^T / sqrt(128). wave w handles batch elem w. ----
    // 20 rows padded to 32: garbage rows/cols masked at the store.
    {
        const int bi = wav;
        const int r0 = bi * N_PERM;
        const bf16* qb = &rB.qk.q[0][0];
        const bf16* kb = &rB.qk.k[0][0];
        f32x4 c00 = zf, c01 = zf, c10 = zf, c11 = zf;
        #pragma unroll
        for (int kt = 0; kt < 4; ++kt) {
            int kof = kt * 32 + lq * 8;
            s16x8 a0 = frag_lds(qb, r0 + l15,      DMP, kof, 15);
            s16x8 a1 = frag_lds(qb, r0 + 16 + l15, DMP, kof, 15);
            s16x8 k0 = frag_lds(kb, r0 + l15,      DMP, kof, 15);
            s16x8 k1 = frag_lds(kb, r0 + 16 + l15, DMP, kof, 15);
            c00 = MFMA16(a0, k0, c00);  c01 = MFMA16(a0, k1, c01);
            c10 = MFMA16(a1, k0, c10);  c11 = MFMA16(a1, k1, c11);
        }
        const float scl = 0.08838834764831845f;
        #pragma unroll
        for (int r = 0; r < 4; ++r) {
            int pr = lq * 4 + r;          // 0..15, always < 20
            int qc = l15;
            rC.p.s.sc[bi][pr][qc] = c00[r] * scl;
            if (qc + 16 < N_PERM) rC.p.s.sc[bi][pr][qc + 16] = c01[r] * scl;
            if (pr + 16 < N_PERM) {
                rC.p.s.sc[bi][pr + 16][qc] = c10[r] * scl;
                if (qc + 16 < N_PERM) rC.p.s.sc[bi][pr + 16][qc + 16] = c11[r] * scl;
            }
        }
    }
    __syncthreads();

    // ---- stage 6: row softmax, then column sums ----
    if (tid < TB * N_PERM) {
        int bi = tid / N_PERM, row = tid % N_PERM;
        float* scrow = rC.p.s.sc[bi][row];
        float mx = -1e30f;
        #pragma unroll
        for (int qq = 0; qq < N_PERM; ++qq) mx = fmaxf(mx, scrow[qq]);
        float sum = 0.f;
        #pragma unroll
        for (int qq = 0; qq < N_PERM; ++qq) { float e = __expf(scrow[qq] - mx); scrow[qq] = e; sum += e; }
        float inv = 1.f / sum;
        #pragma unroll
        for (int qq = 0; qq < N_PERM; ++qq) scrow[qq] *= inv;
    }
    __syncthreads();
    if (tid < TB * N_PERM) {
        int bi = tid / N_PERM, col = tid % N_PERM;
        float cs = 0.f;
        #pragma unroll
        for (int p = 0; p < N_PERM; ++p) cs += rC.p.s.sc[bi][p][col];
        rC.p.cs[bi][col] = cs;
    }
    __syncthreads();

    // ---- stage 7: pooled = colsum(attn) @ v ----
    for (int idx = tid; idx < TB * DMP; idx += 256) {
        int bi = idx >> 7, j = idx & (DMP - 1);
        float acc = 0.f;
        #pragma unroll
        for (int qq = 0; qq < N_PERM; ++qq)
            acc += rC.p.cs[bi][qq] * b2f(rA.v[bi * N_PERM + qq][j]);
        rC.p.pooled[bi][j] = acc;
    }
    __syncthreads();

    // ---- stage 8: hr = relu(pooled @ Wr + br), bf16 weights, col reused x4 ----
    {
        const bf16* wr = wp + OFF_WR;
        float a0 = brv[tid], a1 = a0, a2 = a0, a3 = a0;
        #pragma unroll 4
        for (int kk = 0; kk < DMP; ++kk) {
            float wv = b2f(wr[kk * HID + tid]);
            a0 += rC.p.pooled[0][kk] * wv;
            a1 += rC.p.pooled[1][kk] * wv;
            a2 += rC.p.pooled[2][kk] * wv;
            a3 += rC.p.pooled[3][kk] * wv;
        }
        rC.p.hr[0][tid] = fmaxf(a0, 0.f);
        rC.p.hr[1][tid] = fmaxf(a1, 0.f);
        rC.p.hr[2][tid] = fmaxf(a2, 0.f);
        rC.p.hr[3][tid] = fmaxf(a3, 0.f);
    }
    __syncthreads();

    // ---- stage 9: heads, 8-way split-K then reduce ----
    {
        int o = tid & 31, cch = tid >> 5;
        int bi = o >> 3, rr = o & 7;
        bool is_mean = rr < ACT;
        int a = rr & (ACT - 1);
        const float* W = is_mean ? Wm : Wsc;
        float part = 0.f;
        int k0 = cch * 32;
        #pragma unroll 8
        for (int kk = k0; kk < k0 + 32; ++kk) part += rC.p.hr[bi][kk] * W[kk * ACT + a];
        rC.p.s.red[o][cch] = part;    // red overlays sc (dead after stage 6)
    }
    __syncthreads();
    if (tid < 32) {
        int o = tid, bi = o >> 3, rr = o & 7;
        bool is_mean = rr < ACT;
        int a = rr & (ACT - 1);
        float acc = is_mean ? bm[a] : bsv[a];
        #pragma unroll
        for (int c = 0; c < 8; ++c) acc += rC.p.s.red[o][c];
        if (!is_mean) acc = fminf(fmaxf(acc, -20.f), 2.f);
        out[(is_mean ? 0 : BATCH * ACT) + (b0 + bi) * ACT + a] = acc;
    }
}

extern "C" void kernel_launch(void* const* d_in, const int* in_sizes, int n_in,
                              void* d_out, int out_size, void* d_ws, size_t ws_size,
                              hipStream_t stream) {
    (void)in_sizes; (void)n_in; (void)out_size; (void)ws_size;
    const float* obs = (const float*)d_in[0];
    const float* ag  = (const float*)d_in[1];
    const float* g   = (const float*)d_in[2];
    const float* W1  = (const float*)d_in[3];
    const float* b1  = (const float*)d_in[4];
    const float* W2  = (const float*)d_in[5];
    const float* b2  = (const float*)d_in[6];
    const float* Wq  = (const float*)d_in[7];
    const float* bq  = (const float*)d_in[8];
    const float* Wk  = (const float*)d_in[9];
    const float* bk  = (const float*)d_in[10];
    const float* Wv  = (const float*)d_in[11];
    const float* bv  = (const float*)d_in[12];
    const float* Wr  = (const float*)d_in[13];
    const float* br  = (const float*)d_in[14];
    const float* Wm  = (const float*)d_in[15];
    const float* bm  = (const float*)d_in[16];
    const float* Ws  = (const float*)d_in[17];
    const float* bs  = (const float*)d_in[18];
    const int*  edges    = (const int*)d_in[19];
    const int*  pred_ids = (const int*)d_in[20];
    float* out = (float*)d_out;
    bf16*  wp  = (bf16*)d_ws;

    prepack_kernel<<<(PACK_TOTAL + 255) / 256, 256, 0, stream>>>(W1, W2, Wq, Wk, Wv, Wr, wp);
    actor_main<<<BATCH / TB, 256, 0, stream>>>(
        obs, ag, g, b1, b2, bq, bk, bv, br, Wm, bm, Ws, bs,
        edges, pred_ids, wp, out);
}

// Round 7
// 368.883 us; speedup vs baseline: 22.0771x; 1.1521x over previous
//
#include <hip/hip_runtime.h>
#include <hip/hip_bf16.h>

#define NB_OBJ   5
#define DIM_BODY 10
#define DIM_OBJ  15
#define N_PERM   20
#define HID      256
#define DMP      128
#define ACT      4
#define BATCH    32768
#define GOAL_DIM 30
#define DIN      19
#define OBS_LEN  85
#define TB       4                 // batch elements per block
#define MROWS    80                // TB * N_PERM

typedef __hip_bfloat16 bf16;
typedef __attribute__((ext_vector_type(8))) short s16x8;   // 8 bf16 = 4 VGPRs
typedef __attribute__((ext_vector_type(4))) short s16x4;   // 4 bf16 = 8 B
typedef __attribute__((ext_vector_type(4))) float f32x4;

#define MFMA16(a, b, c) __builtin_amdgcn_mfma_f32_16x16x32_bf16((a), (b), (c), 0, 0, 0)

// ---- packed-weight offsets in d_ws (bf16 elements) ----
// tiled layout: [nt][kt][c(4)][n16(16)][j(8)], value = W[kt*32+c*8+j][nt*16+n16]
// (A/B fragment layouts are lane-symmetric: same bytes serve either operand)
#define OFF_W1   0        // NT=16, KT=1  -> 8192
#define OFF_W2   8192     // NT=8,  KT=8  -> 32768
#define OFF_WQ   40960    // NT=8,  KT=4  -> 16384
#define OFF_WK   57344
#define OFF_WV   73728
#define OFF_WR   90112    // NT=16, KT=4  -> 32768
#define PACK_TOTAL 122880

__device__ __forceinline__ float b2f(bf16 x) { return __bfloat162float(x); }
__device__ __forceinline__ bf16  f2b(float x) { return __float2bfloat16(x); }

// XOR block swizzle: element [m][k] lives at column ((k>>3) ^ (m&bprm))*8 + (k&7)
__device__ __forceinline__ s16x8 frag_lds(const bf16* base, int m, int stride, int kof, int bprm) {
    int phys = (((kof >> 3) ^ (m & bprm)) << 3);
    return *(const s16x8*)(base + m * stride + phys);
}

// C^T epilogue: lane owns fixed m, regs r = 4 consecutive n -> one b64 write
__device__ __forceinline__ void store_c4(bf16* base, int m, int stride, int n0,
                                         int bprm, f32x4 acc, f32x4 bs, bool do_relu) {
    s16x4 w;
    #pragma unroll
    for (int r = 0; r < 4; ++r) {
        float v = acc[r] + bs[r];
        if (do_relu) v = fmaxf(v, 0.f);
        bf16 t = f2b(v);
        w[r] = *(const short*)&t;
    }
    int blk = ((n0 >> 3) ^ (m & bprm));
    *(s16x4*)(base + m * stride + blk * 8 + (n0 & 7)) = w;
}

// ================= prepack: fp32 weights -> bf16 fragment-tiled layout =================
__device__ __forceinline__ void pack_tiled(const float* __restrict__ W, int Kact, int N,
                                           int KT, bf16* __restrict__ dst, int idx) {
    int tile = idx >> 9;            // nt*KT + kt
    int r    = idx & 511;
    int kt   = tile % KT, nt = tile / KT;
    int c    = r >> 7;
    int rem  = r & 127;
    int n16  = rem >> 3, j = rem & 7;
    int k    = kt * 32 + c * 8 + j;
    float v  = (k < Kact) ? W[k * N + nt * 16 + n16] : 0.f;
    dst[idx] = __float2bfloat16(v);
}

__global__ __launch_bounds__(256) void prepack_kernel(
    const float* __restrict__ W1, const float* __restrict__ W2,
    const float* __restrict__ Wq, const float* __restrict__ Wk,
    const float* __restrict__ Wv, const float* __restrict__ Wr,
    bf16* __restrict__ ws) {
    int idx = blockIdx.x * 256 + threadIdx.x;
    if      (idx < 8192)   pack_tiled(W1,  19, 256, 1, ws + OFF_W1, idx);
    else if (idx < 40960)  pack_tiled(W2, 256, 128, 8, ws + OFF_W2, idx - 8192);
    else if (idx < 57344)  pack_tiled(Wq, 128, 128, 4, ws + OFF_WQ, idx - 40960);
    else if (idx < 73728)  pack_tiled(Wk, 128, 128, 4, ws + OFF_WK, idx - 57344);
    else if (idx < 90112)  pack_tiled(Wv, 128, 128, 4, ws + OFF_WV, idx - 73728);
    else if (idx < PACK_TOTAL) pack_tiled(Wr, 128, 256, 4, ws + OFF_WR, idx - 90112);
}

// ================= main fused kernel =================
__global__ __launch_bounds__(256, 2) void actor_main(
    const float* __restrict__ obs, const float* __restrict__ ag, const float* __restrict__ g,
    const float* __restrict__ b1, const float* __restrict__ b2v,
    const float* __restrict__ bqv, const float* __restrict__ bkv, const float* __restrict__ bvv,
    const float* __restrict__ brv,
    const float* __restrict__ Wm, const float* __restrict__ bm,
    const float* __restrict__ Wsc, const float* __restrict__ bsv,
    const int* __restrict__ edges, const int* __restrict__ pred_ids,
    const bf16* __restrict__ wp, float* __restrict__ out)
{
    const int b0   = blockIdx.x * TB;
    const int tid  = threadIdx.x;
    const int lane = tid & 63;
    const int wav  = tid >> 6;
    const int l15  = lane & 15;
    const int lq   = lane >> 4;

    // ---- LDS: three union regions, total exactly 81,920 B (2 blocks/CU) ----
    __shared__ __align__(16) union {
        struct {
            float obs_[TB][OBS_LEN];
            float dg[TB][GOAL_DIM];
            int   edg[N_PERM * 2];
            int   prd[N_PERM * 3];
            bf16  inp[MROWS][40];       // K padded 19->32, row stride 40
        } a;                            // 8,640 B (dead after MLP1)
        bf16 v[MROWS][DMP];             // 20,480 B (written at QKV, plain layout)
    } rA;
    __shared__ __align__(16) union {
        bf16 hall[MROWS][HID];          // 40,960 B (dead after MLP2)
        struct { bf16 q[MROWS][DMP]; bf16 k[MROWS][DMP]; } qk;
    } rB;
    __shared__ __align__(16) union {
        bf16 x[MROWS][DMP];             // 20,480 B (dead after QKV)
        struct {
            union { float sc[TB][N_PERM][N_PERM]; float red[32][8]; } s;
            float cs[TB][N_PERM];
            bf16  pooled[16][DMP];      // rows 4..15 zeroed (stage-8 B pad)
            float hr[TB][HID];
        } p;                            // 14,912 B
    } rC;

    const f32x4 zf = {0.f, 0.f, 0.f, 0.f};

    // ---- stage 0: inputs -> LDS ----
    for (int i = tid; i < TB * OBS_LEN; i += 256)
        ((float*)rA.a.obs_)[i] = obs[b0 * OBS_LEN + i];
    for (int i = tid; i < TB * GOAL_DIM; i += 256)
        ((float*)rA.a.dg)[i] = g[b0 * GOAL_DIM + i] - ag[b0 * GOAL_DIM + i];
    if (tid < N_PERM * 2) rA.a.edg[tid] = edges[tid];
    if (tid < N_PERM * 3) rA.a.prd[tid] = pred_ids[tid];
    __syncthreads();

    // ---- stage 1: build 80 x 32 (19 + zero pad) edge inputs, bf16 ----
    for (int idx = tid; idx < MROWS * 32; idx += 256) {
        int m = idx >> 5, c = idx & 31;
        int bi = m / N_PERM, p = m - bi * N_PERM;
        float v = 0.f;
        if      (c < 10) v = rA.a.obs_[bi][c];
        else if (c < 13) v = rA.a.dg[bi][rA.a.prd[p * 3 + (c - 10)]];
        else if (c < 16) v = rA.a.obs_[bi][DIM_BODY + rA.a.edg[p * 2 + 0] * DIM_OBJ + (c - 13)];
        else if (c < 19) v = rA.a.obs_[bi][DIM_BODY + rA.a.edg[p * 2 + 1] * DIM_OBJ + (c - 16)];
        rA.a.inp[m][c] = f2b(v);
    }
    __syncthreads();

    // ---- stage 2: MLP1 (19->256). D^T = W1^T · inp^T; wave w: nt in [4w,4w+4) ----
    {
        s16x8 xfr[5];
        #pragma unroll
        for (int mt = 0; mt < 5; ++mt)
            xfr[mt] = *(const s16x8*)(&rA.a.inp[mt * 16 + l15][lq * 8]);
        #pragma unroll
        for (int ntl = 0; ntl < 4; ++ntl) {
            int nt = wav * 4 + ntl;
            s16x8 wfr = *(const s16x8*)(wp + OFF_W1 + nt * 512 + (lq * 16 + l15) * 8);
            f32x4 bs = *(const f32x4*)(b1 + nt * 16 + lq * 4);
            int n0 = nt * 16 + lq * 4;
            #pragma unroll
            for (int mt = 0; mt < 5; ++mt) {
                f32x4 acc = MFMA16(wfr, xfr[mt], zf);
                store_c4(&rB.hall[0][0], mt * 16 + l15, HID, n0, 31, acc, bs, true);
            }
        }
    }
    __syncthreads();

    // ---- stage 3: MLP2 (256->128). wave w: nt {2w,2w+1}, KT=8 ----
    {
        int nt0 = wav * 2, nt1 = nt0 + 1;
        f32x4 acc0[5], acc1[5];
        #pragma unroll
        for (int mt = 0; mt < 5; ++mt) { acc0[mt] = zf; acc1[mt] = zf; }
        #pragma unroll
        for (int kt = 0; kt < 8; ++kt) {
            s16x8 wf0 = *(const s16x8*)(wp + OFF_W2 + (nt0 * 8 + kt) * 512 + (lq * 16 + l15) * 8);
            s16x8 wf1 = *(const s16x8*)(wp + OFF_W2 + (nt1 * 8 + kt) * 512 + (lq * 16 + l15) * 8);
            #pragma unroll
            for (int mt = 0; mt < 5; ++mt) {
                s16x8 a = frag_lds(&rB.hall[0][0], mt * 16 + l15, HID, kt * 32 + lq * 8, 31);
                acc0[mt] = MFMA16(wf0, a, acc0[mt]);
                acc1[mt] = MFMA16(wf1, a, acc1[mt]);
            }
        }
        f32x4 bs0 = *(const f32x4*)(b2v + nt0 * 16 + lq * 4);
        f32x4 bs1 = *(const f32x4*)(b2v + nt1 * 16 + lq * 4);
        #pragma unroll
        for (int mt = 0; mt < 5; ++mt) {
            int m = mt * 16 + l15;
            store_c4(&rC.x[0][0], m, DMP, nt0 * 16 + lq * 4, 15, acc0[mt], bs0, true);
            store_c4(&rC.x[0][0], m, DMP, nt1 * 16 + lq * 4, 15, acc1[mt], bs1, true);
        }
    }
    __syncthreads();   // hall reads done -> q/k may overwrite; x visible to all

    // ---- stage 4: QKV (128 -> 3x128). per matrix: nt {2w,2w+1}, KT=4 ----
    #pragma unroll
    for (int mat = 0; mat < 3; ++mat) {
        const bf16*  wpm  = wp + (mat == 0 ? OFF_WQ : (mat == 1 ? OFF_WK : OFF_WV));
        const float* bias = (mat == 0 ? bqv : (mat == 1 ? bkv : bvv));
        int nt0 = wav * 2, nt1 = nt0 + 1;
        f32x4 acc0[5], acc1[5];
        #pragma unroll
        for (int mt = 0; mt < 5; ++mt) { acc0[mt] = zf; acc1[mt] = zf; }
        #pragma unroll
        for (int kt = 0; kt < 4; ++kt) {
            s16x8 wf0 = *(const s16x8*)(wpm + (nt0 * 4 + kt) * 512 + (lq * 16 + l15) * 8);
            s16x8 wf1 = *(const s16x8*)(wpm + (nt1 * 4 + kt) * 512 + (lq * 16 + l15) * 8);
            #pragma unroll
            for (int mt = 0; mt < 5; ++mt) {
                s16x8 a = frag_lds(&rC.x[0][0], mt * 16 + l15, DMP, kt * 32 + lq * 8, 15);
                acc0[mt] = MFMA16(wf0, a, acc0[mt]);
                acc1[mt] = MFMA16(wf1, a, acc1[mt]);
            }
        }
        f32x4 bs0 = *(const f32x4*)(bias + nt0 * 16 + lq * 4);
        f32x4 bs1 = *(const f32x4*)(bias + nt1 * 16 + lq * 4);
        bf16* dst = (mat == 0) ? &rB.qk.q[0][0] : (mat == 1) ? &rB.qk.k[0][0] : &rA.v[0][0];
        int bprm = (mat == 2) ? 0 : 15;   // v plain, q/k swizzled
        #pragma unroll
        for (int mt = 0; mt < 5; ++mt) {
            int m = mt * 16 + l15;
            store_c4(dst, m, DMP, nt0 * 16 + lq * 4, bprm, acc0[mt], bs0, false);
            store_c4(dst, m, DMP, nt1 * 16 + lq * 4, bprm, acc1[mt], bs1, false);
        }
    }
    __syncthreads();

    // ---- stage 5: scores = q k^T / sqrt(128). wave w = batch elem w ----
    {
        const int bi = wav;
        const int r0 = bi * N_PERM;
        const bf16* qb = &rB.qk.q[0][0];
        const bf16* kb = &rB.qk.k[0][0];
        f32x4 c00 = zf, c01 = zf, c10 = zf, c11 = zf;
        #pragma unroll
        for (int kt = 0; kt < 4; ++kt) {
            int kof = kt * 32 + lq * 8;
            s16x8 a0 = frag_lds(qb, r0 + l15,      DMP, kof, 15);
            s16x8 a1 = frag_lds(qb, r0 + 16 + l15, DMP, kof, 15);
            s16x8 k0 = frag_lds(kb, r0 + l15,      DMP, kof, 15);
            s16x8 k1 = frag_lds(kb, r0 + 16 + l15, DMP, kof, 15);
            c00 = MFMA16(a0, k0, c00);  c01 = MFMA16(a0, k1, c01);
            c10 = MFMA16(a1, k0, c10);  c11 = MFMA16(a1, k1, c11);
        }
        const float scl = 0.08838834764831845f;
        #pragma unroll
        for (int r = 0; r < 4; ++r) {
            int pr = lq * 4 + r;          // 0..15 < 20
            int qc = l15;
            rC.p.s.sc[bi][pr][qc] = c00[r] * scl;
            if (qc + 16 < N_PERM) rC.p.s.sc[bi][pr][qc + 16] = c01[r] * scl;
            if (pr + 16 < N_PERM) {
                rC.p.s.sc[bi][pr + 16][qc] = c10[r] * scl;
                if (qc + 16 < N_PERM) rC.p.s.sc[bi][pr + 16][qc + 16] = c11[r] * scl;
            }
        }
    }
    __syncthreads();

    // ---- stage 6: row softmax, then column sums ----
    if (tid < TB * N_PERM) {
        int bi = tid / N_PERM, row = tid % N_PERM;
        float* scrow = rC.p.s.sc[bi][row];
        float mx = -1e30f;
        #pragma unroll
        for (int qq = 0; qq < N_PERM; ++qq) mx = fmaxf(mx, scrow[qq]);
        float sum = 0.f;
        #pragma unroll
        for (int qq = 0; qq < N_PERM; ++qq) { float e = __expf(scrow[qq] - mx); scrow[qq] = e; sum += e; }
        float inv = 1.f / sum;
        #pragma unroll
        for (int qq = 0; qq < N_PERM; ++qq) scrow[qq] *= inv;
    }
    __syncthreads();
    if (tid < TB * N_PERM) {
        int bi = tid / N_PERM, col = tid % N_PERM;
        float cs = 0.f;
        #pragma unroll
        for (int p = 0; p < N_PERM; ++p) cs += rC.p.s.sc[bi][p][col];
        rC.p.cs[bi][col] = cs;
    }
    __syncthreads();

    // ---- stage 7: pooled = colsum(attn) @ v (2-wide), bf16 store + zero pad ----
    {
        int bi = tid >> 6, jp = tid & 63, j0 = jp * 2;
        float a0 = 0.f, a1 = 0.f;
        #pragma unroll
        for (int qq = 0; qq < N_PERM; ++qq) {
            unsigned w = *(const unsigned*)(&rA.v[bi * N_PERM + qq][j0]);
            float c = rC.p.cs[bi][qq];
            a0 += c * __uint_as_float(w << 16);
            a1 += c * __uint_as_float(w & 0xffff0000u);
        }
        bf16 t0 = f2b(a0), t1 = f2b(a1);
        unsigned pk = (unsigned)(*(const unsigned short*)&t0)
                    | ((unsigned)(*(const unsigned short*)&t1) << 16);
        *(unsigned*)(&rC.p.pooled[bi][j0]) = pk;
        for (int i = tid; i < 768; i += 256) {          // zero rows 4..15
            int row = 4 + (i >> 6), c2 = (i & 63) * 2;
            *(unsigned*)(&rC.p.pooled[row][c2]) = 0u;
        }
    }
    __syncthreads();

    // ---- stage 8: hr = relu(pooled @ Wr + br) via MFMA (D^T = Wr^T · pooled^T) ----
    {
        s16x8 pfr[4];
        #pragma unroll
        for (int kt = 0; kt < 4; ++kt)
            pfr[kt] = *(const s16x8*)(&rC.p.pooled[l15][kt * 32 + lq * 8]);
        f32x4 acc[4];
        #pragma unroll
        for (int i = 0; i < 4; ++i) acc[i] = zf;
        #pragma unroll
        for (int kt = 0; kt < 4; ++kt)
            #pragma unroll
            for (int i = 0; i < 4; ++i) {
                int nt = wav * 4 + i;
                s16x8 wf = *(const s16x8*)(wp + OFF_WR + (nt * 4 + kt) * 512 + (lq * 16 + l15) * 8);
                acc[i] = MFMA16(wf, pfr[kt], acc[i]);
            }
        if (l15 < 4) {
            #pragma unroll
            for (int i = 0; i < 4; ++i) {
                int n0 = (wav * 4 + i) * 16 + lq * 4;
                f32x4 bs = *(const f32x4*)(brv + n0);
                f32x4 o;
                #pragma unroll
                for (int r = 0; r < 4; ++r) o[r] = fmaxf(acc[i][r] + bs[r], 0.f);
                *(f32x4*)(&rC.p.hr[l15][n0]) = o;
            }
        }
    }
    __syncthreads();

    // ---- stage 9: heads, 8-way split-K then reduce ----
    {
        int o = tid & 31, cch = tid >> 5;
        int bi = o >> 3, rr = o & 7;
        bool is_mean = rr < ACT;
        int a = rr & (ACT - 1);
        const float* W = is_mean ? Wm : Wsc;
        float part = 0.f;
        int k0 = cch * 32;
        #pragma unroll 8
        for (int kk = k0; kk < k0 + 32; ++kk) part += rC.p.hr[bi][kk] * W[kk * ACT + a];
        rC.p.s.red[o][cch] = part;    // red overlays sc (dead after stage 6)
    }
    __syncthreads();
    if (tid < 32) {
        int o = tid, bi = o >> 3, rr = o & 7;
        bool is_mean = rr < ACT;
        int a = rr & (ACT - 1);
        float acc = is_mean ? bm[a] : bsv[a];
        #pragma unroll
        for (int c = 0; c < 8; ++c) acc += rC.p.s.red[o][c];
        if (!is_mean) acc = fminf(fmaxf(acc, -20.f), 2.f);
        out[(is_mean ? 0 : BATCH * ACT) + (b0 + bi) * ACT + a] = acc;
    }
}

extern "C" void kernel_launch(void* const* d_in, const int* in_sizes, int n_in,
                              void* d_out, int out_size, void* d_ws, size_t ws_size,
                              hipStream_t stream) {
    (void)in_sizes; (void)n_in; (void)out_size; (void)ws_size;
    const float* obs = (const float*)d_in[0];
    const float* ag  = (const float*)d_in[1];
    const float* g   = (const float*)d_in[2];
    const float* W1  = (const float*)d_in[3];
    const float* b1  = (const float*)d_in[4];
    const float* W2  = (const float*)d_in[5];
    const float* b2  = (const float*)d_in[6];
    const float* Wq  = (const float*)d_in[7];
    const float* bq  = (const float*)d_in[8];
    const float* Wk  = (const float*)d_in[9];
    const float* bk  = (const float*)d_in[10];
    const float* Wv  = (const float*)d_in[11];
    const float* bv  = (const float*)d_in[12];
    const float* Wr  = (const float*)d_in[13];
    const float* br  = (const float*)d_in[14];
    const float* Wm  = (const float*)d_in[15];
    const float* bm  = (const float*)d_in[16];
    const float* Ws  = (const float*)d_in[17];
    const float* bs  = (const float*)d_in[18];
    const int*  edges    = (const int*)d_in[19];
    const int*  pred_ids = (const int*)d_in[20];
    float* out = (float*)d_out;
    bf16*  wp  = (bf16*)d_ws;

    prepack_kernel<<<(PACK_TOTAL + 255) / 256, 256, 0, stream>>>(W1, W2, Wq, Wk, Wv, Wr, wp);
    actor_main<<<BATCH / TB, 256, 0, stream>>>(
        obs, ag, g, b1, b2, bq, bk, bv, br, Wm, bm, Ws, bs,
        edges, pred_ids, wp, out);
}